// Round 8
// baseline (53.755 us; speedup 1.0000x reference)
//
#include <hip/hip_runtime.h>
#include <hip/hip_bf16.h>

// Shapes (fixed by the reference): B=1, M=N=256, O=P=12, C=128, D=32
#define N_ 256
#define M_ 256
#define O_ 12
#define C_ 128
#define D_ 32
#define S2 16          // n-splits (16 n per block)
#define KBROW 393216   // bytes per kb m-row = N*O*D*4

typedef __attribute__((ext_vector_type(8))) short short8;   // 8 x bf16
typedef __attribute__((ext_vector_type(4))) float floatx4;  // MFMA acc

// async global->LDS DMA, 16B/lane: LDS dst = uniform base + lane*16,
// global src is per-lane (m173).
#define GLD16(GSRC, LDST) \
    __builtin_amdgcn_global_load_lds( \
        (const __attribute__((address_space(1))) void*)(GSRC), \
        (__attribute__((address_space(3))) void*)(LDST), 16, 0, 0)

static __device__ __forceinline__ short2 pk2(float a, float b) {
    union { __hip_bfloat162 h; short2 s; } u;
    u.h = __float22bfloat162_rn(make_float2(a, b));  // v_cvt_pk_bf16_f32 RNE
    return u.s;
}

static __device__ __forceinline__ short f2bf(float f) {
    unsigned u = __float_as_uint(f);
    unsigned r = u + 0x7FFFu + ((u >> 16) & 1u);  // RNE
    return (short)(r >> 16);
}

static __device__ __forceinline__ float bf2f(short s) {
    return __uint_as_float(((unsigned)(unsigned short)s) << 16);
}

// ---- spatial6b: contiguous-kb streaming, wave-per-o, B built on the fly -
// part16[m][s][o][c] (bf16) = sum over the block's 16 n of kb x (x*mask*Ws).
// Block (mt, sck): 16 m-rows x 16 n, 768 threads = 12 waves (wave w = o).
// Per n-step: DMA full rows kb[m0+r][n][0..1536B) -> LDS (24 KB), swizzled
// via pre-swizzled SOURCE (LDS dst linear, rule 21). NBUF=4, counted
// vmcnt(10). Block (0,0) additionally computes rk[p,o,c] after its epilogue.
__global__ __launch_bounds__(768, 3) void spatial6b_kernel(
    const float* __restrict__ kb, const float* __restrict__ x,
    const float* __restrict__ mask, const float* __restrict__ Ws,
    const float* __restrict__ fkb, const float* __restrict__ Wr,
    short* __restrict__ part16, float* __restrict__ rk)
{
    const int mt  = blockIdx.x;   // 0..15
    const int sck = blockIdx.y;   // 0..15
    const int t = threadIdx.x;
    const int lane = t & 63;
    const int w = t >> 6;         // wave = o (0..11)
    const int l15 = lane & 15;
    const int lk  = lane >> 4;
    const int m0 = mt * 16;
    const int n0 = sck * 16;

    __shared__ __align__(16) char Abuf[4 * 24576];   // 96 KB
    __shared__ float mskL[16];

    if (t < 16) mskL[t] = mask[n0 + t];
    asm volatile("s_waitcnt lgkmcnt(0)" ::: "memory");  // mskL visible pre-barrier

    // staging: wave w covers 16B-slots j in [w*128, w*128+128) of the
    // 1536-slot [16 r][96 s] step tile; slot (r,s) holds logical (r, s^(r&7)).
    const int j0 = w * 128 + lane;
    const int j1 = j0 + 64;
    const int r0 = j0 / 96, s0j = j0 % 96;
    const int r1 = j1 / 96, s1j = j1 % 96;
    const char* kbc = (const char*)kb;
    const char* src0 = kbc + (size_t)(m0 + r0) * KBROW + (size_t)n0 * 1536
                       + (size_t)((s0j ^ (r0 & 7)) * 16);
    const char* src1 = kbc + (size_t)(m0 + r1) * KBROW + (size_t)n0 * 1536
                       + (size_t)((s1j ^ (r1 & 7)) * 16);
    char* dst0 = Abuf + w * 2048;
    char* dst1 = Abuf + w * 2048 + 1024;

#define STAGE(BIX, S) { \
    GLD16(src0 + (size_t)(S) * 1536, dst0 + (BIX) * 24576); \
    GLD16(src1 + (size_t)(S) * 1536, dst1 + (BIX) * 24576); }

    // per-lane Ws fragment (held in VGPRs): wsr[cg][i] = Ws[lk*8+i][cg*16+l15]
    float wsr[8][8];
#pragma unroll
    for (int cg = 0; cg < 8; ++cg)
#pragma unroll
        for (int i = 0; i < 8; ++i)
            wsr[cg][i] = Ws[(lk * 8 + i) * C_ + cg * 16 + l15];

    // A-read offsets: logical slot q = w*8 + lk*2 + {0,1} of row r=l15
    const int off0 = l15 * 1536 + (((w * 8 + lk * 2    ) ^ (l15 & 7)) * 16);
    const int off1 = l15 * 1536 + (((w * 8 + lk * 2 + 1) ^ (l15 & 7)) * 16);

    // x[n][o][c]: same layout as old xmm; mask applied via mskL
    const float* xb = x + ((size_t)n0 * O_ + w) * C_ + l15;

    floatx4 acc[8];
#pragma unroll
    for (int cg = 0; cg < 8; ++cg)
#pragma unroll
        for (int q = 0; q < 4; ++q) acc[cg][q] = 0.f;

    STAGE(0, 0);
    STAGE(1, 1);

    float xvA[8], xvB[8];
#pragma unroll
    for (int cg = 0; cg < 8; ++cg) xvA[cg] = xb[cg * 16];   // x for s=0

    // Per phase: vmcnt(10) guarantees stage-s landed (FIFO: at most
    // [stage s+1(2), stage s+2(2), x(8)] = 12 outstanding; 10 retires the
    // 2 oldest = stage-s only).
#define PHASE(S, BIX, XC, XN) { \
    asm volatile("s_waitcnt vmcnt(10)" ::: "memory"); \
    __builtin_amdgcn_s_barrier(); \
    if ((S) + 2 < 16) STAGE(((BIX) + 2) & 3, (S) + 2); \
    const float mk_ = mskL[S]; \
    const char* ab_ = Abuf + (BIX) * 24576; \
    const floatx4 a0_ = *(const floatx4*)(ab_ + off0); \
    const floatx4 a1_ = *(const floatx4*)(ab_ + off1); \
    union { short8 v; short2 p2[4]; } au_; \
    au_.p2[0] = pk2(a0_[0], a0_[1]); au_.p2[1] = pk2(a0_[2], a0_[3]); \
    au_.p2[2] = pk2(a1_[0], a1_[1]); au_.p2[3] = pk2(a1_[2], a1_[3]); \
    _Pragma("unroll") \
    for (int cg = 0; cg < 8; ++cg) { \
        const float xm_ = XC[cg] * mk_; \
        union { short8 v; short2 p2[4]; } bu_; \
        bu_.p2[0] = pk2(xm_ * wsr[cg][0], xm_ * wsr[cg][1]); \
        bu_.p2[1] = pk2(xm_ * wsr[cg][2], xm_ * wsr[cg][3]); \
        bu_.p2[2] = pk2(xm_ * wsr[cg][4], xm_ * wsr[cg][5]); \
        bu_.p2[3] = pk2(xm_ * wsr[cg][6], xm_ * wsr[cg][7]); \
        acc[cg] = __builtin_amdgcn_mfma_f32_16x16x32_bf16(au_.v, bu_.v, acc[cg], 0, 0, 0); \
    } \
    if ((S) + 1 < 16) { \
        _Pragma("unroll") \
        for (int cg = 0; cg < 8; ++cg) \
            XN[cg] = xb[(size_t)((S) + 1) * (O_ * C_) + cg * 16]; \
    } }

    for (int sb = 0; sb < 16; sb += 4) {
        PHASE(sb + 0, 0, xvA, xvB)
        PHASE(sb + 1, 1, xvB, xvA)
        PHASE(sb + 2, 2, xvA, xvB)
        PHASE(sb + 3, 3, xvB, xvA)
    }
#undef PHASE
#undef STAGE

    // C/D: col = lane&15, row = (lane>>4)*4 + reg  [verified rounds 2-7]
    // part16[m][s][o][c], bf16 RNE
#pragma unroll
    for (int cg = 0; cg < 8; ++cg) {
        const int c = cg * 16 + l15;
#pragma unroll
        for (int j = 0; j < 4; ++j) {
            const int m = m0 + lk * 4 + j;
            part16[(((size_t)m * S2 + sck) * O_ + w) * C_ + c] = f2bf(acc[cg][j]);
        }
    }

    // block (0,0): compute rk[p,o,c] = sum_d fkb[p,o,d]*Wr[d,c]
    if (mt == 0 && sck == 0) {
#pragma unroll 2
        for (int i = t; i < O_ * O_ * C_; i += 768) {
            const int c  = i & (C_ - 1);
            const int po = i >> 7;
            const float* f = fkb + po * D_;
            float a = 0.f;
#pragma unroll
            for (int d = 0; d < D_; ++d) a = fmaf(f[d], Wr[d * C_ + c], a);
            rk[i] = a;
        }
    }
}

// ---- fiber4: out[m,p,c] = (sum_o y1[o,c] * rk[p,o,c])/12 + bias[c],
//      y1[o,c] = sum_s bf2f(part16[m,s,o,c])
__global__ __launch_bounds__(256) void fiber4_kernel(
    const short* __restrict__ part16, const float* __restrict__ rkv,
    const float* __restrict__ bias, float* __restrict__ out)
{
    const int m = blockIdx.x;
    const int t = threadIdx.x;
    __shared__ float y1L[O_][C_];   // 6 KB

    if (t < 192) {                  // o = t>>4, c-octet = t&15
        const int o  = t >> 4;
        const int c0 = (t & 15) * 8;
        float a[8];
#pragma unroll
        for (int i = 0; i < 8; ++i) a[i] = 0.f;
#pragma unroll
        for (int s = 0; s < S2; ++s) {
            const short8 v = *reinterpret_cast<const short8*>(
                part16 + (((size_t)m * S2 + s) * O_ + o) * C_ + c0);
#pragma unroll
            for (int i = 0; i < 8; ++i) a[i] += bf2f(v[i]);
        }
#pragma unroll
        for (int i = 0; i < 8; ++i) y1L[o][c0 + i] = a[i];
    }
    __syncthreads();

#pragma unroll
    for (int k = t; k < O_ * C_; k += 256) {
        const int p = k >> 7;
        const int c = k & (C_ - 1);
        float a = 0.f;
#pragma unroll
        for (int o = 0; o < O_; ++o)
            a = fmaf(y1L[o][c], rkv[(p * O_ + o) * C_ + c], a);
        out[((size_t)m * O_ + p) * C_ + c] = a * (1.f / 12.f) + bias[c];
    }
}

// ---------------- fallback (round-1) path, used only if ws is small ------
__global__ __launch_bounds__(256) void spatial_old_kernel(
    const float* __restrict__ x, const float* __restrict__ kb,
    const float* __restrict__ mask, const float* __restrict__ Ws,
    float* __restrict__ y1)
{
    const int bid = blockIdx.x;
    const int m = bid / O_, o = bid % O_;
    const int tid = threadIdx.x;
    const int h = tid >> 7, c = tid & (C_ - 1);
    __shared__ float kbs[2][8][D_];
    __shared__ float msk[N_];
    __shared__ float Ts[2][D_][C_];
    msk[tid] = mask[tid];
    float T[D_];
#pragma unroll
    for (int d = 0; d < D_; ++d) T[d] = 0.f;
    const float* kb_mo = kb + (size_t)m * (N_ * O_ * D_) + o * D_;
    const int j_ld = c >> 4, d_ld = (c & 15) * 2;
    for (int chunk = 0; chunk < 16; ++chunk) {
        const int n0 = h * 128 + chunk * 8;
        __syncthreads();
        float2 v = *reinterpret_cast<const float2*>(
            kb_mo + (size_t)(n0 + j_ld) * (O_ * D_) + d_ld);
        kbs[h][j_ld][d_ld] = v.x;
        kbs[h][j_ld][d_ld + 1] = v.y;
        __syncthreads();
#pragma unroll
        for (int j = 0; j < 8; ++j) {
            const int n = n0 + j;
            const float xv = x[(n * O_ + o) * C_ + c] * msk[n];
#pragma unroll
            for (int d = 0; d < D_; ++d) T[d] = fmaf(kbs[h][j][d], xv, T[d]);
        }
    }
#pragma unroll
    for (int d = 0; d < D_; ++d) Ts[h][d][c] = T[d];
    __syncthreads();
    if (h == 0) {
        float a = 0.f;
#pragma unroll
        for (int d = 0; d < D_; ++d)
            a = fmaf(Ts[0][d][c] + Ts[1][d][c], Ws[d * C_ + c], a);
        y1[((size_t)m * O_ + o) * C_ + c] = a;
    }
}

__global__ __launch_bounds__(256) void fiber_old_kernel(
    const float* __restrict__ y1, const float* __restrict__ rkv,
    const float* __restrict__ bias, float* __restrict__ out)
{
    int idx = blockIdx.x * 256 + threadIdx.x;
    if (idx >= M_ * O_ * C_) return;
    int c = idx & (C_ - 1);
    int p = (idx >> 7) % O_;
    int m = idx / (O_ * C_);
    float a = 0.f;
#pragma unroll
    for (int o = 0; o < O_; ++o)
        a = fmaf(y1[(m * O_ + o) * C_ + c], rkv[(p * O_ + o) * C_ + c], a);
    out[idx] = a * (1.0f / 12.0f) + bias[c];
}

__global__ __launch_bounds__(256) void rot_proj_kernel(
    const float* __restrict__ fkb, const float* __restrict__ Wr,
    float* __restrict__ rk)
{
    int idx = blockIdx.x * 256 + threadIdx.x;
    if (idx >= O_ * O_ * C_) return;
    int c  = idx & (C_ - 1);
    int po = idx >> 7;
    const float* f = fkb + po * D_;
    float acc = 0.f;
#pragma unroll
    for (int d = 0; d < D_; ++d) acc = fmaf(f[d], Wr[d * C_ + c], acc);
    rk[idx] = acc;
}

extern "C" void kernel_launch(void* const* d_in, const int* in_sizes, int n_in,
                              void* d_out, int out_size, void* d_ws, size_t ws_size,
                              hipStream_t stream)
{
    const float* x    = (const float*)d_in[0];  // (1,256,12,128)
    const float* kb   = (const float*)d_in[1];  // (1,256,256,12,32)
    const float* fkb  = (const float*)d_in[2];  // (12,12,32)
    const float* mask = (const float*)d_in[3];  // (1,256)
    const float* Wsp  = (const float*)d_in[4];  // (32,128)
    const float* Wrt  = (const float*)d_in[5];  // (32,128)
    const float* bias = (const float*)d_in[6];  // (128,)
    float* out = (float*)d_out;                 // (1,256,12,128)

    const size_t RK_F    = (size_t)O_ * O_ * C_;        // 18432 floats
    const size_t PART_E  = (size_t)M_ * S2 * O_ * C_;   // 6291456 bf16
    const size_t need    = RK_F * 4 + PART_E * 2;       // ~12.7 MB

    float* rk = (float*)d_ws;

    if (ws_size >= need) {
        short* part16 = (short*)(rk + RK_F);
        spatial6b_kernel<<<dim3(16, 16), 768, 0, stream>>>(
            kb, x, mask, Wsp, fkb, Wrt, part16, rk);
        fiber4_kernel<<<M_, 256, 0, stream>>>(part16, rk, bias, out);
    } else {
        float* y1 = rk + RK_F;
        rot_proj_kernel<<<(O_ * O_ * C_ + 255) / 256, 256, 0, stream>>>(fkb, Wrt, rk);
        spatial_old_kernel<<<M_ * O_, 256, 0, stream>>>(x, kb, mask, Wsp, y1);
        fiber_old_kernel<<<(M_ * O_ * C_ + 255) / 256, 256, 0, stream>>>(y1, rk, bias, out);
    }
}

// Round 9
// 53.495 us; speedup vs baseline: 1.0049x; 1.0049x over previous
//
#include <hip/hip_runtime.h>
#include <hip/hip_bf16.h>

// Shapes (fixed by the reference): B=1, M=N=256, O=P=12, C=128, D=32
#define N_ 256
#define M_ 256
#define O_ 12
#define C_ 128
#define D_ 32
#define S2 16          // n-splits (16 n per block)
#define KBROW 393216   // bytes per kb m-row = N*O*D*4

typedef __attribute__((ext_vector_type(8))) short short8;   // 8 x bf16
typedef __attribute__((ext_vector_type(4))) float floatx4;  // MFMA acc

// async global->LDS DMA, 16B/lane: LDS dst = uniform base + lane*16,
// global src is per-lane (m173).
#define GLD16(GSRC, LDST) \
    __builtin_amdgcn_global_load_lds( \
        (const __attribute__((address_space(1))) void*)(GSRC), \
        (__attribute__((address_space(3))) void*)(LDST), 16, 0, 0)

static __device__ __forceinline__ short2 pk2(float a, float b) {
    union { __hip_bfloat162 h; short2 s; } u;
    u.h = __float22bfloat162_rn(make_float2(a, b));  // v_cvt_pk_bf16_f32 RNE
    return u.s;
}

static __device__ __forceinline__ short f2bf(float f) {
    unsigned u = __float_as_uint(f);
    unsigned r = u + 0x7FFFu + ((u >> 16) & 1u);  // RNE
    return (short)(r >> 16);
}

static __device__ __forceinline__ float bf2f(short s) {
    return __uint_as_float(((unsigned)(unsigned short)s) << 16);
}

// ---- spatial6c: contiguous-kb streaming, wave-per-o, B built on the fly -
// part16[m][s][o][c] (bf16) = sum over the block's 16 n of kb x (x*mask*Ws).
// Block (mt, sck): 16 m-rows x 16 n, 768 threads = 12 waves (wave w = o).
// Per n-step: DMA full rows kb[m0+r][n][0..1536B) -> LDS (24 KB), swizzled
// via pre-swizzled SOURCE (LDS dst linear, rule 21). NBUF=4, counted
// vmcnt(10). Block (0,0) additionally computes rk[p,o,c] after its epilogue.
//
// waves_per_eu(3,3): LDS (98.8 KB) caps us at 1 block/CU = 3 waves/SIMD, so
// pin the register budget to 168 VGPR/wave. Without this the compiler
// targeted ~6 waves/SIMD (VGPR=76) and SANK the loop-invariant wsr[8][8]
// loads into the phase loop -- 64 global loads/phase that also poisoned the
// vmcnt(10) counting (round-8 regression).
__global__ __attribute__((amdgpu_flat_work_group_size(768, 768),
                          amdgpu_waves_per_eu(3, 3)))
void spatial6c_kernel(
    const float* __restrict__ kb, const float* __restrict__ x,
    const float* __restrict__ mask, const float* __restrict__ Ws,
    const float* __restrict__ fkb, const float* __restrict__ Wr,
    short* __restrict__ part16, float* __restrict__ rk)
{
    const int mt  = blockIdx.x;   // 0..15
    const int sck = blockIdx.y;   // 0..15
    const int t = threadIdx.x;
    const int lane = t & 63;
    const int w = t >> 6;         // wave = o (0..11)
    const int l15 = lane & 15;
    const int lk  = lane >> 4;
    const int m0 = mt * 16;
    const int n0 = sck * 16;

    __shared__ __align__(16) char Abuf[4 * 24576];   // 96 KB
    __shared__ float mskL[16];

    if (t < 16) mskL[t] = mask[n0 + t];
    asm volatile("s_waitcnt lgkmcnt(0)" ::: "memory");  // mskL visible pre-barrier

    // staging: wave w covers 16B-slots j in [w*128, w*128+128) of the
    // 1536-slot [16 r][96 s] step tile; slot (r,s) holds logical (r, s^(r&7)).
    const int j0 = w * 128 + lane;
    const int j1 = j0 + 64;
    const int r0 = j0 / 96, s0j = j0 % 96;
    const int r1 = j1 / 96, s1j = j1 % 96;
    const char* kbc = (const char*)kb;
    const char* src0 = kbc + (size_t)(m0 + r0) * KBROW + (size_t)n0 * 1536
                       + (size_t)((s0j ^ (r0 & 7)) * 16);
    const char* src1 = kbc + (size_t)(m0 + r1) * KBROW + (size_t)n0 * 1536
                       + (size_t)((s1j ^ (r1 & 7)) * 16);
    char* dst0 = Abuf + w * 2048;
    char* dst1 = Abuf + w * 2048 + 1024;

#define STAGE(BIX, S) { \
    GLD16(src0 + (size_t)(S) * 1536, dst0 + (BIX) * 24576); \
    GLD16(src1 + (size_t)(S) * 1536, dst1 + (BIX) * 24576); }

    // per-lane Ws fragment (held in VGPRs): wsr[cg][i] = Ws[lk*8+i][cg*16+l15]
    float wsr[8][8];
#pragma unroll
    for (int cg = 0; cg < 8; ++cg)
#pragma unroll
        for (int i = 0; i < 8; ++i)
            wsr[cg][i] = Ws[(lk * 8 + i) * C_ + cg * 16 + l15];

    // A-read offsets: logical slot q = w*8 + lk*2 + {0,1} of row r=l15
    const int off0 = l15 * 1536 + (((w * 8 + lk * 2    ) ^ (l15 & 7)) * 16);
    const int off1 = l15 * 1536 + (((w * 8 + lk * 2 + 1) ^ (l15 & 7)) * 16);

    // x[n][o][c]; mask applied via mskL
    const float* xb = x + ((size_t)n0 * O_ + w) * C_ + l15;

    floatx4 acc[8];
#pragma unroll
    for (int cg = 0; cg < 8; ++cg)
#pragma unroll
        for (int q = 0; q < 4; ++q) acc[cg][q] = 0.f;

    STAGE(0, 0);
    STAGE(1, 1);

    float xvA[8], xvB[8];
#pragma unroll
    for (int cg = 0; cg < 8; ++cg) xvA[cg] = xb[cg * 16];   // x for s=0

    // Per phase: vmcnt(10) guarantees stage-s landed (FIFO: at most
    // [stage s+1(2), stage s+2(2), x(8)] = 12 outstanding; 10 retires the
    // 2 oldest = stage-s only).
#define PHASE(S, BIX, XC, XN) { \
    asm volatile("s_waitcnt vmcnt(10)" ::: "memory"); \
    __builtin_amdgcn_s_barrier(); \
    if ((S) + 2 < 16) STAGE(((BIX) + 2) & 3, (S) + 2); \
    const float mk_ = mskL[S]; \
    const char* ab_ = Abuf + (BIX) * 24576; \
    const floatx4 a0_ = *(const floatx4*)(ab_ + off0); \
    const floatx4 a1_ = *(const floatx4*)(ab_ + off1); \
    union { short8 v; short2 p2[4]; } au_; \
    au_.p2[0] = pk2(a0_[0], a0_[1]); au_.p2[1] = pk2(a0_[2], a0_[3]); \
    au_.p2[2] = pk2(a1_[0], a1_[1]); au_.p2[3] = pk2(a1_[2], a1_[3]); \
    _Pragma("unroll") \
    for (int cg = 0; cg < 8; ++cg) { \
        const float xm_ = XC[cg] * mk_; \
        union { short8 v; short2 p2[4]; } bu_; \
        bu_.p2[0] = pk2(xm_ * wsr[cg][0], xm_ * wsr[cg][1]); \
        bu_.p2[1] = pk2(xm_ * wsr[cg][2], xm_ * wsr[cg][3]); \
        bu_.p2[2] = pk2(xm_ * wsr[cg][4], xm_ * wsr[cg][5]); \
        bu_.p2[3] = pk2(xm_ * wsr[cg][6], xm_ * wsr[cg][7]); \
        acc[cg] = __builtin_amdgcn_mfma_f32_16x16x32_bf16(au_.v, bu_.v, acc[cg], 0, 0, 0); \
    } \
    if ((S) + 1 < 16) { \
        _Pragma("unroll") \
        for (int cg = 0; cg < 8; ++cg) \
            XN[cg] = xb[(size_t)((S) + 1) * (O_ * C_) + cg * 16]; \
    } }

    for (int sb = 0; sb < 16; sb += 4) {
        PHASE(sb + 0, 0, xvA, xvB)
        PHASE(sb + 1, 1, xvB, xvA)
        PHASE(sb + 2, 2, xvA, xvB)
        PHASE(sb + 3, 3, xvB, xvA)
    }
#undef PHASE
#undef STAGE

    // C/D: col = lane&15, row = (lane>>4)*4 + reg  [verified rounds 2-8]
    // part16[m][s][o][c], bf16 RNE
#pragma unroll
    for (int cg = 0; cg < 8; ++cg) {
        const int c = cg * 16 + l15;
#pragma unroll
        for (int j = 0; j < 4; ++j) {
            const int m = m0 + lk * 4 + j;
            part16[(((size_t)m * S2 + sck) * O_ + w) * C_ + c] = f2bf(acc[cg][j]);
        }
    }

    // block (0,0): compute rk[p,o,c] = sum_d fkb[p,o,d]*Wr[d,c]
    if (mt == 0 && sck == 0) {
#pragma unroll 2
        for (int i = t; i < O_ * O_ * C_; i += 768) {
            const int c  = i & (C_ - 1);
            const int po = i >> 7;
            const float* f = fkb + po * D_;
            float a = 0.f;
#pragma unroll
            for (int d = 0; d < D_; ++d) a = fmaf(f[d], Wr[d * C_ + c], a);
            rk[i] = a;
        }
    }
}

// ---- fiber4: out[m,p,c] = (sum_o y1[o,c] * rk[p,o,c])/12 + bias[c],
//      y1[o,c] = sum_s bf2f(part16[m,s,o,c])
__global__ __launch_bounds__(256) void fiber4_kernel(
    const short* __restrict__ part16, const float* __restrict__ rkv,
    const float* __restrict__ bias, float* __restrict__ out)
{
    const int m = blockIdx.x;
    const int t = threadIdx.x;
    __shared__ float y1L[O_][C_];   // 6 KB

    if (t < 192) {                  // o = t>>4, c-octet = t&15
        const int o  = t >> 4;
        const int c0 = (t & 15) * 8;
        float a[8];
#pragma unroll
        for (int i = 0; i < 8; ++i) a[i] = 0.f;
#pragma unroll
        for (int s = 0; s < S2; ++s) {
            const short8 v = *reinterpret_cast<const short8*>(
                part16 + (((size_t)m * S2 + s) * O_ + o) * C_ + c0);
#pragma unroll
            for (int i = 0; i < 8; ++i) a[i] += bf2f(v[i]);
        }
#pragma unroll
        for (int i = 0; i < 8; ++i) y1L[o][c0 + i] = a[i];
    }
    __syncthreads();

#pragma unroll
    for (int k = t; k < O_ * C_; k += 256) {
        const int p = k >> 7;
        const int c = k & (C_ - 1);
        float a = 0.f;
#pragma unroll
        for (int o = 0; o < O_; ++o)
            a = fmaf(y1L[o][c], rkv[(p * O_ + o) * C_ + c], a);
        out[((size_t)m * O_ + p) * C_ + c] = a * (1.f / 12.f) + bias[c];
    }
}

// ---------------- fallback (round-1) path, used only if ws is small ------
__global__ __launch_bounds__(256) void spatial_old_kernel(
    const float* __restrict__ x, const float* __restrict__ kb,
    const float* __restrict__ mask, const float* __restrict__ Ws,
    float* __restrict__ y1)
{
    const int bid = blockIdx.x;
    const int m = bid / O_, o = bid % O_;
    const int tid = threadIdx.x;
    const int h = tid >> 7, c = tid & (C_ - 1);
    __shared__ float kbs[2][8][D_];
    __shared__ float msk[N_];
    __shared__ float Ts[2][D_][C_];
    msk[tid] = mask[tid];
    float T[D_];
#pragma unroll
    for (int d = 0; d < D_; ++d) T[d] = 0.f;
    const float* kb_mo = kb + (size_t)m * (N_ * O_ * D_) + o * D_;
    const int j_ld = c >> 4, d_ld = (c & 15) * 2;
    for (int chunk = 0; chunk < 16; ++chunk) {
        const int n0 = h * 128 + chunk * 8;
        __syncthreads();
        float2 v = *reinterpret_cast<const float2*>(
            kb_mo + (size_t)(n0 + j_ld) * (O_ * D_) + d_ld);
        kbs[h][j_ld][d_ld] = v.x;
        kbs[h][j_ld][d_ld + 1] = v.y;
        __syncthreads();
#pragma unroll
        for (int j = 0; j < 8; ++j) {
            const int n = n0 + j;
            const float xv = x[(n * O_ + o) * C_ + c] * msk[n];
#pragma unroll
            for (int d = 0; d < D_; ++d) T[d] = fmaf(kbs[h][j][d], xv, T[d]);
        }
    }
#pragma unroll
    for (int d = 0; d < D_; ++d) Ts[h][d][c] = T[d];
    __syncthreads();
    if (h == 0) {
        float a = 0.f;
#pragma unroll
        for (int d = 0; d < D_; ++d)
            a = fmaf(Ts[0][d][c] + Ts[1][d][c], Ws[d * C_ + c], a);
        y1[((size_t)m * O_ + o) * C_ + c] = a;
    }
}

__global__ __launch_bounds__(256) void fiber_old_kernel(
    const float* __restrict__ y1, const float* __restrict__ rkv,
    const float* __restrict__ bias, float* __restrict__ out)
{
    int idx = blockIdx.x * 256 + threadIdx.x;
    if (idx >= M_ * O_ * C_) return;
    int c = idx & (C_ - 1);
    int p = (idx >> 7) % O_;
    int m = idx / (O_ * C_);
    float a = 0.f;
#pragma unroll
    for (int o = 0; o < O_; ++o)
        a = fmaf(y1[(m * O_ + o) * C_ + c], rkv[(p * O_ + o) * C_ + c], a);
    out[idx] = a * (1.0f / 12.0f) + bias[c];
}

__global__ __launch_bounds__(256) void rot_proj_kernel(
    const float* __restrict__ fkb, const float* __restrict__ Wr,
    float* __restrict__ rk)
{
    int idx = blockIdx.x * 256 + threadIdx.x;
    if (idx >= O_ * O_ * C_) return;
    int c  = idx & (C_ - 1);
    int po = idx >> 7;
    const float* f = fkb + po * D_;
    float acc = 0.f;
#pragma unroll
    for (int d = 0; d < D_; ++d) acc = fmaf(f[d], Wr[d * C_ + c], acc);
    rk[idx] = acc;
}

extern "C" void kernel_launch(void* const* d_in, const int* in_sizes, int n_in,
                              void* d_out, int out_size, void* d_ws, size_t ws_size,
                              hipStream_t stream)
{
    const float* x    = (const float*)d_in[0];  // (1,256,12,128)
    const float* kb   = (const float*)d_in[1];  // (1,256,256,12,32)
    const float* fkb  = (const float*)d_in[2];  // (12,12,32)
    const float* mask = (const float*)d_in[3];  // (1,256)
    const float* Wsp  = (const float*)d_in[4];  // (32,128)
    const float* Wrt  = (const float*)d_in[5];  // (32,128)
    const float* bias = (const float*)d_in[6];  // (128,)
    float* out = (float*)d_out;                 // (1,256,12,128)

    const size_t RK_F    = (size_t)O_ * O_ * C_;        // 18432 floats
    const size_t PART_E  = (size_t)M_ * S2 * O_ * C_;   // 6291456 bf16
    const size_t need    = RK_F * 4 + PART_E * 2;       // ~12.7 MB

    float* rk = (float*)d_ws;

    if (ws_size >= need) {
        short* part16 = (short*)(rk + RK_F);
        spatial6c_kernel<<<dim3(16, 16), 768, 0, stream>>>(
            kb, x, mask, Wsp, fkb, Wrt, part16, rk);
        fiber4_kernel<<<M_, 256, 0, stream>>>(part16, rk, bias, out);
    } else {
        float* y1 = rk + RK_F;
        rot_proj_kernel<<<(O_ * O_ * C_ + 255) / 256, 256, 0, stream>>>(fkb, Wrt, rk);
        spatial_old_kernel<<<M_ * O_, 256, 0, stream>>>(x, kb, mask, Wsp, y1);
        fiber_old_kernel<<<(M_ * O_ * C_ + 255) / 256, 256, 0, stream>>>(y1, rk, bias, out);
    }
}

// Round 10
// 47.866 us; speedup vs baseline: 1.1230x; 1.1176x over previous
//
#include <hip/hip_runtime.h>
#include <hip/hip_bf16.h>

// Shapes (fixed by the reference): B=1, M=N=256, O=P=12, C=128, D=32
#define N_ 256
#define M_ 256
#define O_ 12
#define C_ 128
#define D_ 32
#define S2 32          // n-splits (8 n per block, 512 blocks -> 2 blocks/CU)
#define KBROW 393216   // bytes per kb m-row = N*O*D*4

typedef __attribute__((ext_vector_type(8))) short short8;   // 8 x bf16
typedef __attribute__((ext_vector_type(4))) float floatx4;  // MFMA acc

// async global->LDS DMA, 16B/lane: LDS dst = uniform base + lane*16,
// global src is per-lane (m173).
#define GLD16(GSRC, LDST) \
    __builtin_amdgcn_global_load_lds( \
        (const __attribute__((address_space(1))) void*)(GSRC), \
        (__attribute__((address_space(3))) void*)(LDST), 16, 0, 0)

static __device__ __forceinline__ short2 pk2(float a, float b) {
    union { __hip_bfloat162 h; short2 s; } u;
    u.h = __float22bfloat162_rn(make_float2(a, b));  // v_cvt_pk_bf16_f32 RNE
    return u.s;
}

static __device__ __forceinline__ short f2bf(float f) {
    unsigned u = __float_as_uint(f);
    unsigned r = u + 0x7FFFu + ((u >> 16) & 1u);  // RNE
    return (short)(r >> 16);
}

static __device__ __forceinline__ float bf2f(short s) {
    return __uint_as_float(((unsigned)(unsigned short)s) << 16);
}

// ---- prep2: xmm[n][o][c] = x[n,o,c]*mask[n]  and  rk[p,o,c] -------------
// (restored from round 7 -- its in-loop absence is what regressed rounds 8/9)
__global__ __launch_bounds__(256) void prep2_kernel(
    const float* __restrict__ x, const float* __restrict__ mask,
    const float* __restrict__ fkb, const float* __restrict__ Wr,
    float* __restrict__ xmm, float* __restrict__ rk)
{
    const int b = blockIdx.x;
    const int t = threadIdx.x;
    if (b < 1536) {                       // 1536*256 = 393216 = N*O*C
        const int idx = b * 256 + t;
        const int n = idx / (O_ * C_);
        xmm[idx] = x[idx] * mask[n];
    } else {
        const int idx = (b - 1536) * 256 + t;   // < 18432 = O*O*C
        const int c  = idx & (C_ - 1);
        const int po = idx >> 7;
        const float* f = fkb + po * D_;
        float acc = 0.f;
#pragma unroll
        for (int d = 0; d < D_; ++d) acc = fmaf(f[d], Wr[d * C_ + c], acc);
        rk[idx] = acc;
    }
}

// ---- spatial7: contiguous-kb streaming, wave-per-o, 2 blocks/CU ---------
// part16[m][s][o][c] (bf16) = sum over the block's 8 n of kb x (xmm*Ws).
// Block (mt, sck): 16 m-rows x 8 n, 768 threads = 12 waves (wave w = o).
// Inner loop = round-7 spatial6 (proven fast). NBUF=3 (72 KB LDS) ->
// 2 blocks/CU: two independent barrier domains per CU overlap each other's
// stage-drain with compute. Next-phase x loads issued BEFORE the STAGE so
// the compiler's x-drain doesn't force the critical prefetch to land early.
__global__ __launch_bounds__(768, 3) void spatial7_kernel(
    const float* __restrict__ kb, const float* __restrict__ xmm,
    const float* __restrict__ Ws, short* __restrict__ part16)
{
    const int mt  = blockIdx.x;   // 0..15
    const int sck = blockIdx.y;   // 0..31
    const int t = threadIdx.x;
    const int lane = t & 63;
    const int w = t >> 6;         // wave = o (0..11)
    const int l15 = lane & 15;
    const int lk  = lane >> 4;
    const int m0 = mt * 16;
    const int n0 = sck * 8;

    __shared__ __align__(16) char Abuf[3 * 24576];   // 72 KB

    // staging: wave w covers 16B-slots j in [w*128, w*128+128) of the
    // 1536-slot [16 r][96 s] step tile; slot (r,s) holds logical (r, s^(r&7)).
    const int j0 = w * 128 + lane;
    const int j1 = j0 + 64;
    const int r0 = j0 / 96, s0j = j0 % 96;
    const int r1 = j1 / 96, s1j = j1 % 96;
    const char* kbc = (const char*)kb;
    const char* src0 = kbc + (size_t)(m0 + r0) * KBROW + (size_t)n0 * 1536
                       + (size_t)((s0j ^ (r0 & 7)) * 16);
    const char* src1 = kbc + (size_t)(m0 + r1) * KBROW + (size_t)n0 * 1536
                       + (size_t)((s1j ^ (r1 & 7)) * 16);
    char* dst0 = Abuf + w * 2048;
    char* dst1 = Abuf + w * 2048 + 1024;

#define STAGE(BIX, S) { \
    GLD16(src0 + (size_t)(S) * 1536, dst0 + (BIX) * 24576); \
    GLD16(src1 + (size_t)(S) * 1536, dst1 + (BIX) * 24576); }

    // per-lane Ws fragment (held in VGPRs): wsr[cg][i] = Ws[lk*8+i][cg*16+l15]
    float wsr[8][8];
#pragma unroll
    for (int cg = 0; cg < 8; ++cg)
#pragma unroll
        for (int i = 0; i < 8; ++i)
            wsr[cg][i] = Ws[(lk * 8 + i) * C_ + cg * 16 + l15];

    // A-read offsets: logical slot q = w*8 + lk*2 + {0,1} of row r=l15
    const int off0 = l15 * 1536 + (((w * 8 + lk * 2    ) ^ (l15 & 7)) * 16);
    const int off1 = l15 * 1536 + (((w * 8 + lk * 2 + 1) ^ (l15 & 7)) * 16);

    const float* xb = xmm + ((size_t)n0 * O_ + w) * C_ + l15;

    floatx4 acc[8];
#pragma unroll
    for (int cg = 0; cg < 8; ++cg)
#pragma unroll
        for (int q = 0; q < 4; ++q) acc[cg][q] = 0.f;

    STAGE(0, 0);
    STAGE(1, 1);

    float xvA[8], xvB[8];
#pragma unroll
    for (int cg = 0; cg < 8; ++cg) xvA[cg] = xb[cg * 16];   // x for s=0

    // Per phase: vmcnt(10) retires only the oldest stage (queue holds at
    // most [stage s(2), x(8), stage s+1/s+2(2)]); last phase uses vmcnt(8)
    // so the final stage is deterministically landed (no reliance on
    // natural completion). x loads for s+1 are issued BEFORE STAGE(s+2).
#define PHASE(S, BIX, XC, XN) { \
    if ((S) == 7) asm volatile("s_waitcnt vmcnt(8)" ::: "memory"); \
    else          asm volatile("s_waitcnt vmcnt(10)" ::: "memory"); \
    __builtin_amdgcn_s_barrier(); \
    if ((S) + 1 < 8) { \
        _Pragma("unroll") \
        for (int cg = 0; cg < 8; ++cg) \
            XN[cg] = xb[(size_t)((S) + 1) * (O_ * C_) + cg * 16]; \
    } \
    if ((S) + 2 < 8) STAGE(((S) + 2) % 3, (S) + 2); \
    const char* ab_ = Abuf + (BIX) * 24576; \
    const floatx4 a0_ = *(const floatx4*)(ab_ + off0); \
    const floatx4 a1_ = *(const floatx4*)(ab_ + off1); \
    union { short8 v; short2 p2[4]; } au_; \
    au_.p2[0] = pk2(a0_[0], a0_[1]); au_.p2[1] = pk2(a0_[2], a0_[3]); \
    au_.p2[2] = pk2(a1_[0], a1_[1]); au_.p2[3] = pk2(a1_[2], a1_[3]); \
    _Pragma("unroll") \
    for (int cg = 0; cg < 8; ++cg) { \
        union { short8 v; short2 p2[4]; } bu_; \
        bu_.p2[0] = pk2(XC[cg] * wsr[cg][0], XC[cg] * wsr[cg][1]); \
        bu_.p2[1] = pk2(XC[cg] * wsr[cg][2], XC[cg] * wsr[cg][3]); \
        bu_.p2[2] = pk2(XC[cg] * wsr[cg][4], XC[cg] * wsr[cg][5]); \
        bu_.p2[3] = pk2(XC[cg] * wsr[cg][6], XC[cg] * wsr[cg][7]); \
        acc[cg] = __builtin_amdgcn_mfma_f32_16x16x32_bf16(au_.v, bu_.v, acc[cg], 0, 0, 0); \
    } }

    PHASE(0, 0, xvA, xvB)
    PHASE(1, 1, xvB, xvA)
    PHASE(2, 2, xvA, xvB)
    PHASE(3, 0, xvB, xvA)
    PHASE(4, 1, xvA, xvB)
    PHASE(5, 2, xvB, xvA)
    PHASE(6, 0, xvA, xvB)
    PHASE(7, 1, xvB, xvA)
#undef PHASE
#undef STAGE

    // C/D: col = lane&15, row = (lane>>4)*4 + reg  [verified rounds 2-9]
    // part16[m][s][o][c], bf16 RNE
#pragma unroll
    for (int cg = 0; cg < 8; ++cg) {
        const int c = cg * 16 + l15;
#pragma unroll
        for (int j = 0; j < 4; ++j) {
            const int m = m0 + lk * 4 + j;
            part16[(((size_t)m * S2 + sck) * O_ + w) * C_ + c] = f2bf(acc[cg][j]);
        }
    }
}

// ---- fiber4: out[m,p,c] = (sum_o y1[o,c] * rk[p,o,c])/12 + bias[c],
//      y1[o,c] = sum_s bf2f(part16[m,s,o,c])
__global__ __launch_bounds__(256) void fiber4_kernel(
    const short* __restrict__ part16, const float* __restrict__ rkv,
    const float* __restrict__ bias, float* __restrict__ out)
{
    const int m = blockIdx.x;
    const int t = threadIdx.x;
    __shared__ float y1L[O_][C_];   // 6 KB

    if (t < 192) {                  // o = t>>4, c-octet = t&15
        const int o  = t >> 4;
        const int c0 = (t & 15) * 8;
        float a[8];
#pragma unroll
        for (int i = 0; i < 8; ++i) a[i] = 0.f;
#pragma unroll
        for (int s = 0; s < S2; ++s) {
            const short8 v = *reinterpret_cast<const short8*>(
                part16 + (((size_t)m * S2 + s) * O_ + o) * C_ + c0);
#pragma unroll
            for (int i = 0; i < 8; ++i) a[i] += bf2f(v[i]);
        }
#pragma unroll
        for (int i = 0; i < 8; ++i) y1L[o][c0 + i] = a[i];
    }
    __syncthreads();

#pragma unroll
    for (int k = t; k < O_ * C_; k += 256) {
        const int p = k >> 7;
        const int c = k & (C_ - 1);
        float a = 0.f;
#pragma unroll
        for (int o = 0; o < O_; ++o)
            a = fmaf(y1L[o][c], rkv[(p * O_ + o) * C_ + c], a);
        out[((size_t)m * O_ + p) * C_ + c] = a * (1.f / 12.f) + bias[c];
    }
}

// ---------------- fallback (round-1) path, used only if ws is small ------
__global__ __launch_bounds__(256) void spatial_old_kernel(
    const float* __restrict__ x, const float* __restrict__ kb,
    const float* __restrict__ mask, const float* __restrict__ Ws,
    float* __restrict__ y1)
{
    const int bid = blockIdx.x;
    const int m = bid / O_, o = bid % O_;
    const int tid = threadIdx.x;
    const int h = tid >> 7, c = tid & (C_ - 1);
    __shared__ float kbs[2][8][D_];
    __shared__ float msk[N_];
    __shared__ float Ts[2][D_][C_];
    msk[tid] = mask[tid];
    float T[D_];
#pragma unroll
    for (int d = 0; d < D_; ++d) T[d] = 0.f;
    const float* kb_mo = kb + (size_t)m * (N_ * O_ * D_) + o * D_;
    const int j_ld = c >> 4, d_ld = (c & 15) * 2;
    for (int chunk = 0; chunk < 16; ++chunk) {
        const int n0 = h * 128 + chunk * 8;
        __syncthreads();
        float2 v = *reinterpret_cast<const float2*>(
            kb_mo + (size_t)(n0 + j_ld) * (O_ * D_) + d_ld);
        kbs[h][j_ld][d_ld] = v.x;
        kbs[h][j_ld][d_ld + 1] = v.y;
        __syncthreads();
#pragma unroll
        for (int j = 0; j < 8; ++j) {
            const int n = n0 + j;
            const float xv = x[(n * O_ + o) * C_ + c] * msk[n];
#pragma unroll
            for (int d = 0; d < D_; ++d) T[d] = fmaf(kbs[h][j][d], xv, T[d]);
        }
    }
#pragma unroll
    for (int d = 0; d < D_; ++d) Ts[h][d][c] = T[d];
    __syncthreads();
    if (h == 0) {
        float a = 0.f;
#pragma unroll
        for (int d = 0; d < D_; ++d)
            a = fmaf(Ts[0][d][c] + Ts[1][d][c], Ws[d * C_ + c], a);
        y1[((size_t)m * O_ + o) * C_ + c] = a;
    }
}

__global__ __launch_bounds__(256) void fiber_old_kernel(
    const float* __restrict__ y1, const float* __restrict__ rkv,
    const float* __restrict__ bias, float* __restrict__ out)
{
    int idx = blockIdx.x * 256 + threadIdx.x;
    if (idx >= M_ * O_ * C_) return;
    int c = idx & (C_ - 1);
    int p = (idx >> 7) % O_;
    int m = idx / (O_ * C_);
    float a = 0.f;
#pragma unroll
    for (int o = 0; o < O_; ++o)
        a = fmaf(y1[(m * O_ + o) * C_ + c], rkv[(p * O_ + o) * C_ + c], a);
    out[idx] = a * (1.0f / 12.0f) + bias[c];
}

__global__ __launch_bounds__(256) void rot_proj_kernel(
    const float* __restrict__ fkb, const float* __restrict__ Wr,
    float* __restrict__ rk)
{
    int idx = blockIdx.x * 256 + threadIdx.x;
    if (idx >= O_ * O_ * C_) return;
    int c  = idx & (C_ - 1);
    int po = idx >> 7;
    const float* f = fkb + po * D_;
    float acc = 0.f;
#pragma unroll
    for (int d = 0; d < D_; ++d) acc = fmaf(f[d], Wr[d * C_ + c], acc);
    rk[idx] = acc;
}

extern "C" void kernel_launch(void* const* d_in, const int* in_sizes, int n_in,
                              void* d_out, int out_size, void* d_ws, size_t ws_size,
                              hipStream_t stream)
{
    const float* x    = (const float*)d_in[0];  // (1,256,12,128)
    const float* kb   = (const float*)d_in[1];  // (1,256,256,12,32)
    const float* fkb  = (const float*)d_in[2];  // (12,12,32)
    const float* mask = (const float*)d_in[3];  // (1,256)
    const float* Wsp  = (const float*)d_in[4];  // (32,128)
    const float* Wrt  = (const float*)d_in[5];  // (32,128)
    const float* bias = (const float*)d_in[6];  // (128,)
    float* out = (float*)d_out;                 // (1,256,12,128)

    const size_t RK_F    = (size_t)O_ * O_ * C_;        // 18432 floats
    const size_t PART_E  = (size_t)M_ * S2 * O_ * C_;   // 12582912 bf16
    const size_t XMM_F   = (size_t)N_ * O_ * C_;        // 393216 floats
    const size_t need    = RK_F * 4 + PART_E * 2 + XMM_F * 4;  // ~26.8 MB

    float* rk = (float*)d_ws;

    if (ws_size >= need) {
        short* part16 = (short*)(rk + RK_F);
        float* xmm    = (float*)(part16 + PART_E);
        prep2_kernel<<<1536 + (O_ * O_ * C_) / 256, 256, 0, stream>>>(
            x, mask, fkb, Wrt, xmm, rk);
        spatial7_kernel<<<dim3(16, 32), 768, 0, stream>>>(kb, xmm, Wsp, part16);
        fiber4_kernel<<<M_, 256, 0, stream>>>(part16, rk, bias, out);
    } else {
        float* y1 = rk + RK_F;
        rot_proj_kernel<<<(O_ * O_ * C_ + 255) / 256, 256, 0, stream>>>(fkb, Wrt, rk);
        spatial_old_kernel<<<M_ * O_, 256, 0, stream>>>(x, kb, mask, Wsp, y1);
        fiber_old_kernel<<<(M_ * O_ * C_ + 255) / 256, 256, 0, stream>>>(y1, rk, bias, out);
    }
}

// Round 11
// 38.030 us; speedup vs baseline: 1.4135x; 1.2587x over previous
//
#include <hip/hip_runtime.h>
#include <hip/hip_bf16.h>

// Shapes (fixed by the reference): B=1, M=N=256, O=P=12, C=128, D=32
#define N_ 256
#define M_ 256
#define O_ 12
#define C_ 128
#define D_ 32
#define S2 16          // n-splits (16 n per block, 256 blocks = 1/CU)
#define KBROW 393216   // bytes per kb m-row = N*O*D*4

typedef __attribute__((ext_vector_type(8))) short short8;   // 8 x bf16
typedef __attribute__((ext_vector_type(4))) float floatx4;  // MFMA acc

// async global->LDS DMA, 16B/lane: LDS dst = uniform base + lane*16,
// global src is per-lane (m173).
#define GLD16(GSRC, LDST) \
    __builtin_amdgcn_global_load_lds( \
        (const __attribute__((address_space(1))) void*)(GSRC), \
        (__attribute__((address_space(3))) void*)(LDST), 16, 0, 0)

static __device__ __forceinline__ short2 pk2(float a, float b) {
    union { __hip_bfloat162 h; short2 s; } u;
    u.h = __float22bfloat162_rn(make_float2(a, b));  // v_cvt_pk_bf16_f32 RNE
    return u.s;
}

static __device__ __forceinline__ short f2bf(float f) {
    unsigned u = __float_as_uint(f);
    unsigned r = u + 0x7FFFu + ((u >> 16) & 1u);  // RNE
    return (short)(r >> 16);
}

static __device__ __forceinline__ float bf2f(short s) {
    return __uint_as_float(((unsigned)(unsigned short)s) << 16);
}

// ---- prep2: xmm[n][o][c] = x[n,o,c]*mask[n]  and  rk[p,o,c] -------------
__global__ __launch_bounds__(256) void prep2_kernel(
    const float* __restrict__ x, const float* __restrict__ mask,
    const float* __restrict__ fkb, const float* __restrict__ Wr,
    float* __restrict__ xmm, float* __restrict__ rk)
{
    const int b = blockIdx.x;
    const int t = threadIdx.x;
    if (b < 1536) {                       // 1536*256 = 393216 = N*O*C
        const int idx = b * 256 + t;
        const int n = idx / (O_ * C_);
        xmm[idx] = x[idx] * mask[n];
    } else {
        const int idx = (b - 1536) * 256 + t;   // < 18432 = O*O*C
        const int c  = idx & (C_ - 1);
        const int po = idx >> 7;
        const float* f = fkb + po * D_;
        float acc = 0.f;
#pragma unroll
        for (int d = 0; d < D_; ++d) acc = fmaf(f[d], Wr[d * C_ + c], acc);
        rk[idx] = acc;
    }
}

// ---- spatial8: contiguous-kb DMA + scale-after-MFMA ---------------------
// y1-partial[m,c] += sum_n xm[n][c] * (sum_d bf16(kb[m,n,o,d])*bf16(Ws[d,c]))
// Block (mt, sck): 16 m-rows x 16 n, 768 threads = 12 waves (wave w = o).
// Per phase: stage 2 n (48 KB: 16 rows x 3072 B contiguous), NBUF=2,
// depth-1 prefetch issued right AFTER the barrier -> at phase top everything
// in the vmem queue is one full phase old, so `vmcnt(0) lgkmcnt(0)` drains
// for free and is robust to any compiler-scheduled x loads (no counting).
// B-operand is the CONSTANT bf16 Ws fragment (32 VGPR); per (n,cg):
// t = mfma(kbA, wsb[cg], 0); acc[cg] += xm * t  (x stays fp32 -- never
// rounded; only kb and Ws are bf16).
__global__ __launch_bounds__(768, 3) void spatial8_kernel(
    const float* __restrict__ kb, const float* __restrict__ xmm,
    const float* __restrict__ Ws, short* __restrict__ part16)
{
    const int mt  = blockIdx.x;   // 0..15
    const int sck = blockIdx.y;   // 0..15
    const int t = threadIdx.x;
    const int lane = t & 63;
    const int w = t >> 6;         // wave = o (0..11)
    const int l15 = lane & 15;
    const int lk  = lane >> 4;
    const int m0 = mt * 16;
    const int n0 = sck * 16;

    __shared__ __align__(16) char Abuf[2 * 49152];   // 96 KB

    const char* kbc = (const char*)kb;
    // staging: 3072 16B-chunks per 48KB tile; thread t handles chunks
    // ci = t + g*768 (g=0..3). Chunk ci -> row r=ci/192, slot q'=ci%192;
    // slot q' of row r holds logical chunk q = q' ^ (r&7)  (pre-swizzled
    // SOURCE, LDS dst linear -- rule 21).
#define MKSRC(CI) (kbc + (size_t)(m0 + (CI) / 192) * KBROW \
                       + (size_t)n0 * 1536 \
                       + (size_t)((((CI) % 192) ^ (((CI) / 192) & 7)) * 16))
    const char* s0_ = MKSRC(t);
    const char* s1_ = MKSRC(t + 768);
    const char* s2_ = MKSRC(t + 1536);
    const char* s3_ = MKSRC(t + 2304);
#undef MKSRC
    // wave-uniform LDS dst for group g: g*12288 + w*1024 (+ lane*16 by HW)
#define STAGE(BIX, S) { \
    char* db_ = Abuf + (BIX) * 49152 + w * 1024; \
    GLD16(s0_ + (size_t)(S) * 3072, db_); \
    GLD16(s1_ + (size_t)(S) * 3072, db_ + 12288); \
    GLD16(s2_ + (size_t)(S) * 3072, db_ + 24576); \
    GLD16(s3_ + (size_t)(S) * 3072, db_ + 36864); }

    // constant B fragments: wsb[cg][i] = bf16(Ws[lk*8+i][cg*16+l15])
    short8 wsb[8];
#pragma unroll
    for (int cg = 0; cg < 8; ++cg) {
        short8 v;
#pragma unroll
        for (int i = 0; i < 8; ++i)
            v[i] = f2bf(Ws[(lk * 8 + i) * C_ + cg * 16 + l15]);
        wsb[cg] = v;
    }

    // A-read offsets (swizzled): row r=l15, logical chunk
    // Q = ksub*96 + w*8 + lk*2 + e  ->  slot Q ^ (l15&7)
    const int swz = l15 & 7;
    const int oA0 = l15 * 3072 + w * 128 + (((lk * 2)     ^ swz) * 16);
    const int oA1 = l15 * 3072 + w * 128 + (((lk * 2 + 1) ^ swz) * 16);
    // ksub=1 adds 1536 (xor term independent of ksub)

    const float* xb = xmm + ((size_t)n0 * O_ + w) * C_ + l15;

    floatx4 acc[8];
#pragma unroll
    for (int cg = 0; cg < 8; ++cg)
#pragma unroll
        for (int q = 0; q < 4; ++q) acc[cg][q] = 0.f;
    const floatx4 zc = {0.f, 0.f, 0.f, 0.f};

    STAGE(0, 0);

    float xvA[16], xvB[16];   // [ksub*8+cg], double-buffered across phases
#pragma unroll
    for (int k2 = 0; k2 < 2; ++k2)
#pragma unroll
        for (int cg = 0; cg < 8; ++cg)
            xvA[k2 * 8 + cg] = xb[(size_t)k2 * (O_ * C_) + cg * 16];

#define PHASE(S, XC, XN) { \
    asm volatile("s_waitcnt vmcnt(0) lgkmcnt(0)" ::: "memory"); \
    __builtin_amdgcn_s_barrier(); \
    if ((S) + 1 < 8) { \
        STAGE(((S) + 1) & 1, (S) + 1); \
        _Pragma("unroll") \
        for (int k2 = 0; k2 < 2; ++k2) \
            _Pragma("unroll") \
            for (int cg = 0; cg < 8; ++cg) \
                XN[k2 * 8 + cg] = \
                    xb[(size_t)(2 * ((S) + 1) + k2) * (O_ * C_) + cg * 16]; \
    } \
    const char* ab_ = Abuf + ((S) & 1) * 49152; \
    _Pragma("unroll") \
    for (int ksub = 0; ksub < 2; ++ksub) { \
        const floatx4 a0_ = *(const floatx4*)(ab_ + oA0 + ksub * 1536); \
        const floatx4 a1_ = *(const floatx4*)(ab_ + oA1 + ksub * 1536); \
        union { short8 v; short2 p2[4]; } au_; \
        au_.p2[0] = pk2(a0_[0], a0_[1]); au_.p2[1] = pk2(a0_[2], a0_[3]); \
        au_.p2[2] = pk2(a1_[0], a1_[1]); au_.p2[3] = pk2(a1_[2], a1_[3]); \
        _Pragma("unroll") \
        for (int cg = 0; cg < 8; ++cg) { \
            const floatx4 t_ = __builtin_amdgcn_mfma_f32_16x16x32_bf16( \
                au_.v, wsb[cg], zc, 0, 0, 0); \
            const float xc_ = XC[ksub * 8 + cg]; \
            _Pragma("unroll") \
            for (int q = 0; q < 4; ++q) \
                acc[cg][q] = fmaf(xc_, t_[q], acc[cg][q]); \
        } \
    } }

    PHASE(0, xvA, xvB)
    PHASE(1, xvB, xvA)
    PHASE(2, xvA, xvB)
    PHASE(3, xvB, xvA)
    PHASE(4, xvA, xvB)
    PHASE(5, xvB, xvA)
    PHASE(6, xvA, xvB)
    PHASE(7, xvB, xvA)
#undef PHASE
#undef STAGE

    // C/D: col = lane&15, row = (lane>>4)*4 + reg  [verified rounds 2-10]
    // part16[m][s][o][c], bf16 RNE
#pragma unroll
    for (int cg = 0; cg < 8; ++cg) {
        const int c = cg * 16 + l15;
#pragma unroll
        for (int j = 0; j < 4; ++j) {
            const int m = m0 + lk * 4 + j;
            part16[(((size_t)m * S2 + sck) * O_ + w) * C_ + c] = f2bf(acc[cg][j]);
        }
    }
}

// ---- fiber4: out[m,p,c] = (sum_o y1[o,c] * rk[p,o,c])/12 + bias[c],
//      y1[o,c] = sum_s bf2f(part16[m,s,o,c])
__global__ __launch_bounds__(256) void fiber4_kernel(
    const short* __restrict__ part16, const float* __restrict__ rkv,
    const float* __restrict__ bias, float* __restrict__ out)
{
    const int m = blockIdx.x;
    const int t = threadIdx.x;
    __shared__ float y1L[O_][C_];   // 6 KB

    if (t < 192) {                  // o = t>>4, c-octet = t&15
        const int o  = t >> 4;
        const int c0 = (t & 15) * 8;
        float a[8];
#pragma unroll
        for (int i = 0; i < 8; ++i) a[i] = 0.f;
#pragma unroll
        for (int s = 0; s < S2; ++s) {
            const short8 v = *reinterpret_cast<const short8*>(
                part16 + (((size_t)m * S2 + s) * O_ + o) * C_ + c0);
#pragma unroll
            for (int i = 0; i < 8; ++i) a[i] += bf2f(v[i]);
        }
#pragma unroll
        for (int i = 0; i < 8; ++i) y1L[o][c0 + i] = a[i];
    }
    __syncthreads();

#pragma unroll
    for (int k = t; k < O_ * C_; k += 256) {
        const int p = k >> 7;
        const int c = k & (C_ - 1);
        float a = 0.f;
#pragma unroll
        for (int o = 0; o < O_; ++o)
            a = fmaf(y1L[o][c], rkv[(p * O_ + o) * C_ + c], a);
        out[((size_t)m * O_ + p) * C_ + c] = a * (1.f / 12.f) + bias[c];
    }
}

// ---------------- fallback (round-1) path, used only if ws is small ------
__global__ __launch_bounds__(256) void spatial_old_kernel(
    const float* __restrict__ x, const float* __restrict__ kb,
    const float* __restrict__ mask, const float* __restrict__ Ws,
    float* __restrict__ y1)
{
    const int bid = blockIdx.x;
    const int m = bid / O_, o = bid % O_;
    const int tid = threadIdx.x;
    const int h = tid >> 7, c = tid & (C_ - 1);
    __shared__ float kbs[2][8][D_];
    __shared__ float msk[N_];
    __shared__ float Ts[2][D_][C_];
    msk[tid] = mask[tid];
    float T[D_];
#pragma unroll
    for (int d = 0; d < D_; ++d) T[d] = 0.f;
    const float* kb_mo = kb + (size_t)m * (N_ * O_ * D_) + o * D_;
    const int j_ld = c >> 4, d_ld = (c & 15) * 2;
    for (int chunk = 0; chunk < 16; ++chunk) {
        const int n0 = h * 128 + chunk * 8;
        __syncthreads();
        float2 v = *reinterpret_cast<const float2*>(
            kb_mo + (size_t)(n0 + j_ld) * (O_ * D_) + d_ld);
        kbs[h][j_ld][d_ld] = v.x;
        kbs[h][j_ld][d_ld + 1] = v.y;
        __syncthreads();
#pragma unroll
        for (int j = 0; j < 8; ++j) {
            const int n = n0 + j;
            const float xv = x[(n * O_ + o) * C_ + c] * msk[n];
#pragma unroll
            for (int d = 0; d < D_; ++d) T[d] = fmaf(kbs[h][j][d], xv, T[d]);
        }
    }
#pragma unroll
    for (int d = 0; d < D_; ++d) Ts[h][d][c] = T[d];
    __syncthreads();
    if (h == 0) {
        float a = 0.f;
#pragma unroll
        for (int d = 0; d < D_; ++d)
            a = fmaf(Ts[0][d][c] + Ts[1][d][c], Ws[d * C_ + c], a);
        y1[((size_t)m * O_ + o) * C_ + c] = a;
    }
}

__global__ __launch_bounds__(256) void fiber_old_kernel(
    const float* __restrict__ y1, const float* __restrict__ rkv,
    const float* __restrict__ bias, float* __restrict__ out)
{
    int idx = blockIdx.x * 256 + threadIdx.x;
    if (idx >= M_ * O_ * C_) return;
    int c = idx & (C_ - 1);
    int p = (idx >> 7) % O_;
    int m = idx / (O_ * C_);
    float a = 0.f;
#pragma unroll
    for (int o = 0; o < O_; ++o)
        a = fmaf(y1[(m * O_ + o) * C_ + c], rkv[(p * O_ + o) * C_ + c], a);
    out[idx] = a * (1.0f / 12.0f) + bias[c];
}

__global__ __launch_bounds__(256) void rot_proj_kernel(
    const float* __restrict__ fkb, const float* __restrict__ Wr,
    float* __restrict__ rk)
{
    int idx = blockIdx.x * 256 + threadIdx.x;
    if (idx >= O_ * O_ * C_) return;
    int c  = idx & (C_ - 1);
    int po = idx >> 7;
    const float* f = fkb + po * D_;
    float acc = 0.f;
#pragma unroll
    for (int d = 0; d < D_; ++d) acc = fmaf(f[d], Wr[d * C_ + c], acc);
    rk[idx] = acc;
}

extern "C" void kernel_launch(void* const* d_in, const int* in_sizes, int n_in,
                              void* d_out, int out_size, void* d_ws, size_t ws_size,
                              hipStream_t stream)
{
    const float* x    = (const float*)d_in[0];  // (1,256,12,128)
    const float* kb   = (const float*)d_in[1];  // (1,256,256,12,32)
    const float* fkb  = (const float*)d_in[2];  // (12,12,32)
    const float* mask = (const float*)d_in[3];  // (1,256)
    const float* Wsp  = (const float*)d_in[4];  // (32,128)
    const float* Wrt  = (const float*)d_in[5];  // (32,128)
    const float* bias = (const float*)d_in[6];  // (128,)
    float* out = (float*)d_out;                 // (1,256,12,128)

    const size_t RK_F    = (size_t)O_ * O_ * C_;        // 18432 floats
    const size_t PART_E  = (size_t)M_ * S2 * O_ * C_;   // 6291456 bf16
    const size_t XMM_F   = (size_t)N_ * O_ * C_;        // 393216 floats
    const size_t need    = RK_F * 4 + PART_E * 2 + XMM_F * 4;  // ~14.2 MB

    float* rk = (float*)d_ws;

    if (ws_size >= need) {
        short* part16 = (short*)(rk + RK_F);
        float* xmm    = (float*)(part16 + PART_E);
        prep2_kernel<<<1536 + (O_ * O_ * C_) / 256, 256, 0, stream>>>(
            x, mask, fkb, Wrt, xmm, rk);
        spatial8_kernel<<<dim3(16, 16), 768, 0, stream>>>(kb, xmm, Wsp, part16);
        fiber4_kernel<<<M_, 256, 0, stream>>>(part16, rk, bias, out);
    } else {
        float* y1 = rk + RK_F;
        rot_proj_kernel<<<(O_ * O_ * C_ + 255) / 256, 256, 0, stream>>>(fkb, Wrt, rk);
        spatial_old_kernel<<<M_ * O_, 256, 0, stream>>>(x, kb, mask, Wsp, y1);
        fiber_old_kernel<<<(M_ * O_ * C_ + 255) / 256, 256, 0, stream>>>(y1, rk, bias, out);
    }
}